// Round 1
// baseline (1280.222 us; speedup 1.0000x reference)
//
#include <hip/hip_runtime.h>

typedef unsigned int u32;
typedef unsigned short u16;
typedef __attribute__((ext_vector_type(8))) short short8;
typedef __attribute__((ext_vector_type(8))) unsigned short ushort8v;
typedef __attribute__((ext_vector_type(4))) unsigned short ushort4v;
typedef __attribute__((ext_vector_type(4))) float f32x4;

#define NSRC 50000
#define NTGT 50000
#define NEDGE 640000
#define LDIM 128
#define SLOPE 0.01f

#define MFMA(a, b, c) __builtin_amdgcn_mfma_f32_16x16x32_bf16((a), (b), (c), 0, 0, 0)

// ---------- helpers ----------
__device__ __forceinline__ u16 f2bf(float f) {
  union { float f; u32 u; } v; v.f = f;
  u32 r = v.u + 0x7FFFu + ((v.u >> 16) & 1u);   // RNE
  return (u16)(r >> 16);
}
__device__ __forceinline__ float bf2f(u16 h) {
  union { u32 u; float f; } v; v.u = ((u32)h) << 16; return v.f;
}
__device__ __forceinline__ void g2lds16(const u16* g, u16* l) {
  __builtin_amdgcn_global_load_lds(
      (const __attribute__((address_space(1))) u32*)g,
      (__attribute__((address_space(3))) u32*)l, 16, 0, 0);
}
// 256-thread cooperative panel copy, ITERS * 4096 bytes, global->LDS direct.
template <int ITERS>
__device__ __forceinline__ void stage_panel(const u16* __restrict__ g, u16* lds, int tid) {
#pragma unroll
  for (int it = 0; it < ITERS; ++it)
    g2lds16(g + it * 2048 + tid * 8, lds + it * 2048 + tid * 8);
}

// ---------- weight prep: f32 [K][N] -> bf16 panels pre[kc][n][40], pre[..][j]=W[kc*32+j][n] ----------
__global__ void k_prep(const float* __restrict__ W1, const float* __restrict__ W2,
                       const float* __restrict__ U1, const float* __restrict__ U2,
                       u16* __restrict__ w1p, u16* __restrict__ w2p,
                       u16* __restrict__ u1p, u16* __restrict__ u2p) {
  int id = blockIdx.x * 256 + threadIdx.x;
  const float* src; u16* dst; int N, kc, n;
  if (id < 2048)       { src = W1; dst = w1p; N = 256; int l = id;          kc = l >> 8; n = l & 255; }
  else if (id < 4096)  { src = W2; dst = w2p; N = 256; int l = id - 2048;   kc = l >> 8; n = l & 255; }
  else if (id < 12288) { src = U1; dst = u1p; N = 512; int l = id - 4096;   kc = l >> 9; n = l & 511; }
  else if (id < 14336) { src = U2; dst = u2p; N = 128; int l = id - 12288;  kc = l >> 7; n = l & 127; }
  else return;
  u16* o = dst + ((size_t)kc * N + n) * 40;
  const float* s = src + (size_t)kc * 32 * N + n;
#pragma unroll
  for (int j = 0; j < 32; ++j) o[j] = f2bf(s[(size_t)j * N]);
}

// ---------- counting sort by target ----------
__global__ void k_count(const int* __restrict__ tgt, int* __restrict__ cnt) {
  int e = blockIdx.x * 256 + threadIdx.x;
  if (e < NEDGE) atomicAdd(&cnt[tgt[e]], 1);
}

__global__ void k_scan(const int* __restrict__ cnt, int* __restrict__ rowstart,
                       int* __restrict__ cur) {
  __shared__ int part[1024];
  int tid = threadIdx.x;
  int base = tid * 49;                       // 1024*49 = 50176 >= 50000
  int s = 0;
  for (int i = 0; i < 49; ++i) { int idx = base + i; if (idx < NTGT) s += cnt[idx]; }
  part[tid] = s;
  __syncthreads();
  for (int off = 1; off < 1024; off <<= 1) {
    int v = (tid >= off) ? part[tid - off] : 0;
    __syncthreads();
    part[tid] += v;
    __syncthreads();
  }
  int run = (tid > 0) ? part[tid - 1] : 0;
  for (int i = 0; i < 49; ++i) {
    int idx = base + i;
    if (idx < NTGT) { rowstart[idx] = run; cur[idx] = run; run += cnt[idx]; }
  }
  if (tid == 1023) rowstart[NTGT] = part[1023];
}

__global__ void k_pos(const int* __restrict__ tgt, int* __restrict__ cur, int* __restrict__ pos) {
  int e = blockIdx.x * 256 + threadIdx.x;
  if (e < NEDGE) pos[e] = atomicAdd(&cur[tgt[e]], 1);
}

// ---------- edge MLP: 64 edges/block, 2x (64x256x256) GEMM, msg written target-sorted ----------
__global__ __launch_bounds__(256) void k_edge(
    const float* __restrict__ xs, const int* __restrict__ srcp,
    const float* __restrict__ ea,
    const u16* __restrict__ w1p, const u16* __restrict__ w2p,
    const float* __restrict__ b1, const float* __restrict__ b2,
    const int* __restrict__ pos, u16* __restrict__ msg) {
  __shared__ u16 tile[64][264];    // 33792 B  (input, then t, then msg)
  __shared__ u16 bbuf[10240];      // 20480 B  (one 32-k x 256-col weight panel)
  const int tid = threadIdx.x;
  const int ebase = blockIdx.x * 64;

  // ---- stage A: gather x_s[src] | edge_attr, f32 -> bf16 ----
  {
    const int et = tid >> 2, p = tid & 3;
    const float* srow;
    if (p < 2) {
      int sidx = srcp[ebase + et];
      srow = xs + (size_t)sidx * LDIM + p * 64;
    } else {
      srow = ea + (size_t)(ebase + et) * LDIM + (p - 2) * 64;
    }
    const float4* f4 = (const float4*)srow;
    u16* dst = &tile[et][p * 64];
#pragma unroll
    for (int i = 0; i < 8; ++i) {
      float4 a = f4[2 * i], b = f4[2 * i + 1];
      ushort8v pk = { f2bf(a.x), f2bf(a.y), f2bf(a.z), f2bf(a.w),
                      f2bf(b.x), f2bf(b.y), f2bf(b.z), f2bf(b.w) };
      *(ushort8v*)(dst + i * 8) = pk;
    }
  }
  __syncthreads();

  const int lane = tid & 63, wid = tid >> 6;
  const int quad = lane >> 4, l16 = lane & 15;
  const int colb = wid * 64;

  f32x4 acc[4][4];
#pragma unroll
  for (int a = 0; a < 4; ++a)
#pragma unroll
    for (int b = 0; b < 4; ++b) acc[a][b] = (f32x4){0.f, 0.f, 0.f, 0.f};

  // ---- GEMM1: t = leaky(in @ W1 + b1) ----
  for (int kc = 0; kc < 8; ++kc) {
    stage_panel<5>(w1p + (size_t)kc * 10240, bbuf, tid);
    __syncthreads();
    short8 af[4], bfr[4];
#pragma unroll
    for (int rt = 0; rt < 4; ++rt)
      af[rt] = *(const short8*)&tile[rt * 16 + l16][kc * 32 + quad * 8];
#pragma unroll
    for (int ct = 0; ct < 4; ++ct)
      bfr[ct] = *(const short8*)&bbuf[(colb + ct * 16 + l16) * 40 + quad * 8];
#pragma unroll
    for (int rt = 0; rt < 4; ++rt)
#pragma unroll
      for (int ct = 0; ct < 4; ++ct)
        acc[rt][ct] = MFMA(af[rt], bfr[ct], acc[rt][ct]);
    __syncthreads();
  }
  // epilogue 1 -> tile (bf16)
#pragma unroll
  for (int ct = 0; ct < 4; ++ct) {
    int col = colb + ct * 16 + l16;
    float bias = b1[col];
#pragma unroll
    for (int rt = 0; rt < 4; ++rt)
#pragma unroll
      for (int r = 0; r < 4; ++r) {
        int row = rt * 16 + quad * 4 + r;
        float v = acc[rt][ct][r] + bias;
        v = v > 0.f ? v : SLOPE * v;
        tile[row][col] = f2bf(v);
      }
  }
  __syncthreads();

  // ---- GEMM2: msg = t @ W2 + b2 ----
#pragma unroll
  for (int a = 0; a < 4; ++a)
#pragma unroll
    for (int b = 0; b < 4; ++b) acc[a][b] = (f32x4){0.f, 0.f, 0.f, 0.f};
  for (int kc = 0; kc < 8; ++kc) {
    stage_panel<5>(w2p + (size_t)kc * 10240, bbuf, tid);
    __syncthreads();
    short8 af[4], bfr[4];
#pragma unroll
    for (int rt = 0; rt < 4; ++rt)
      af[rt] = *(const short8*)&tile[rt * 16 + l16][kc * 32 + quad * 8];
#pragma unroll
    for (int ct = 0; ct < 4; ++ct)
      bfr[ct] = *(const short8*)&bbuf[(colb + ct * 16 + l16) * 40 + quad * 8];
#pragma unroll
    for (int rt = 0; rt < 4; ++rt)
#pragma unroll
      for (int ct = 0; ct < 4; ++ct)
        acc[rt][ct] = MFMA(af[rt], bfr[ct], acc[rt][ct]);
    __syncthreads();
  }
  // epilogue 2 -> tile (bf16 msg)
#pragma unroll
  for (int ct = 0; ct < 4; ++ct) {
    int col = colb + ct * 16 + l16;
    float bias = b2[col];
#pragma unroll
    for (int rt = 0; rt < 4; ++rt)
#pragma unroll
      for (int r = 0; r < 4; ++r) {
        int row = rt * 16 + quad * 4 + r;
        tile[row][col] = f2bf(acc[rt][ct][r] + bias);
      }
  }
  __syncthreads();

  // ---- scatter rows to target-sorted msg buffer ----
  {
    const int et = tid >> 2, p = tid & 3;
    const int gp = pos[ebase + et];
    u16* dst = msg + (size_t)gp * 256 + p * 64;
    const u16* sl = &tile[et][p * 64];
#pragma unroll
    for (int i = 0; i < 8; ++i)
      *(ushort8v*)(dst + i * 8) = *(const ushort8v*)(sl + i * 8);
  }
}

// ---------- node update: 32 targets/block; aggregate + (32x512x512) + (32x128x512) + BN partials ----------
__global__ __launch_bounds__(256) void k_node(
    const float* __restrict__ xt, const float* __restrict__ xu,
    const u16* __restrict__ msg, const int* __restrict__ rowstart,
    const u16* __restrict__ u1p, const u16* __restrict__ u2p,
    const float* __restrict__ c1, const float* __restrict__ c2,
    float* __restrict__ h2, float* __restrict__ stats) {
  __shared__ u16 ain[32][520];   // 33280 B : [x_t | agg | x_u] bf16, then h1
  __shared__ u16 bbuf[10240];    // 20480 B
  const int tid = threadIdx.x;
  const int lane = tid & 63, wid = tid >> 6;
  const int quad = lane >> 4, l16 = lane & 15;
  const int tbase = blockIdx.x * 32;

  // ---- stage: one wave per target slot ----
  for (int s = wid; s < 32; s += 4) {
    int t = tbase + s;
    if (t < NTGT) {
      {
        float4 v; int col;
        if (lane < 32) { v = ((const float4*)(xt + (size_t)t * LDIM))[lane]; col = lane * 4; }
        else           { v = ((const float4*)xu)[lane - 32]; col = 384 + (lane - 32) * 4; }
        ushort4v p = { f2bf(v.x), f2bf(v.y), f2bf(v.z), f2bf(v.w) };
        *(ushort4v*)&ain[s][col] = p;
      }
      int rs = rowstart[t], re = rowstart[t + 1];
      const u16* mb = msg + lane * 4;
      f32x4 a0 = {0,0,0,0}, a1 = {0,0,0,0}, a2 = {0,0,0,0}, a3 = {0,0,0,0};
      int r = rs;
      for (; r + 4 <= re; r += 4) {
        ushort4v m0 = *(const ushort4v*)(mb + (size_t)(r    ) * 256);
        ushort4v m1 = *(const ushort4v*)(mb + (size_t)(r + 1) * 256);
        ushort4v m2 = *(const ushort4v*)(mb + (size_t)(r + 2) * 256);
        ushort4v m3 = *(const ushort4v*)(mb + (size_t)(r + 3) * 256);
        a0 += (f32x4){bf2f(m0[0]), bf2f(m0[1]), bf2f(m0[2]), bf2f(m0[3])};
        a1 += (f32x4){bf2f(m1[0]), bf2f(m1[1]), bf2f(m1[2]), bf2f(m1[3])};
        a2 += (f32x4){bf2f(m2[0]), bf2f(m2[1]), bf2f(m2[2]), bf2f(m2[3])};
        a3 += (f32x4){bf2f(m3[0]), bf2f(m3[1]), bf2f(m3[2]), bf2f(m3[3])};
      }
      for (; r < re; ++r) {
        ushort4v m0 = *(const ushort4v*)(mb + (size_t)r * 256);
        a0 += (f32x4){bf2f(m0[0]), bf2f(m0[1]), bf2f(m0[2]), bf2f(m0[3])};
      }
      f32x4 sum = a0 + a1 + a2 + a3;
      ushort4v p = { f2bf(sum[0]), f2bf(sum[1]), f2bf(sum[2]), f2bf(sum[3]) };
      *(ushort4v*)&ain[s][128 + lane * 4] = p;
    } else {
      ushort8v z = {0,0,0,0,0,0,0,0};
      *(ushort8v*)&ain[s][lane * 8] = z;   // zero the 512 data cols
    }
  }
  __syncthreads();

  // ---- GEMM1: h1 = leaky(ain @ U1 + c1), N=512 in two col halves ----
  f32x4 acc[2][2][4];   // [half][rowtile][coltile]
#pragma unroll
  for (int h = 0; h < 2; ++h)
#pragma unroll
    for (int a = 0; a < 2; ++a)
#pragma unroll
      for (int b = 0; b < 4; ++b) acc[h][a][b] = (f32x4){0.f, 0.f, 0.f, 0.f};

  for (int kc = 0; kc < 16; ++kc) {
#pragma unroll
    for (int h = 0; h < 2; ++h) {
      stage_panel<5>(u1p + ((size_t)kc * 512 + h * 256) * 40, bbuf, tid);
      __syncthreads();
      short8 af[2], bfr[4];
#pragma unroll
      for (int rt = 0; rt < 2; ++rt)
        af[rt] = *(const short8*)&ain[rt * 16 + l16][kc * 32 + quad * 8];
#pragma unroll
      for (int ct = 0; ct < 4; ++ct)
        bfr[ct] = *(const short8*)&bbuf[(wid * 64 + ct * 16 + l16) * 40 + quad * 8];
#pragma unroll
      for (int rt = 0; rt < 2; ++rt)
#pragma unroll
        for (int ct = 0; ct < 4; ++ct)
          acc[h][rt][ct] = MFMA(af[rt], bfr[ct], acc[h][rt][ct]);
      __syncthreads();
    }
  }
  // epilogue 1 -> ain (h1, bf16)
#pragma unroll
  for (int h = 0; h < 2; ++h)
#pragma unroll
    for (int ct = 0; ct < 4; ++ct) {
      int col = h * 256 + wid * 64 + ct * 16 + l16;
      float cb = c1[col];
#pragma unroll
      for (int rt = 0; rt < 2; ++rt)
#pragma unroll
        for (int r = 0; r < 4; ++r) {
          int row = rt * 16 + quad * 4 + r;
          float v = acc[h][rt][ct][r] + cb;
          v = v > 0.f ? v : SLOPE * v;
          ain[row][col] = f2bf(v);
        }
    }
  __syncthreads();

  // ---- GEMM2: h2 = h1 @ U2 + c2, N=128 ----
  const int colb2 = wid * 32;
  f32x4 acc2[2][2];
#pragma unroll
  for (int a = 0; a < 2; ++a)
#pragma unroll
    for (int b = 0; b < 2; ++b) acc2[a][b] = (f32x4){0.f, 0.f, 0.f, 0.f};
  for (int kc = 0; kc < 16; ++kc) {
    stage_panel<3>(u2p + (size_t)kc * 5120, bbuf, tid);
    __syncthreads();
    short8 af[2], bfr[2];
#pragma unroll
    for (int rt = 0; rt < 2; ++rt)
      af[rt] = *(const short8*)&ain[rt * 16 + l16][kc * 32 + quad * 8];
#pragma unroll
    for (int ct = 0; ct < 2; ++ct)
      bfr[ct] = *(const short8*)&bbuf[(colb2 + ct * 16 + l16) * 40 + quad * 8];
#pragma unroll
    for (int rt = 0; rt < 2; ++rt)
#pragma unroll
      for (int ct = 0; ct < 2; ++ct)
        acc2[rt][ct] = MFMA(af[rt], bfr[ct], acc2[rt][ct]);
    __syncthreads();
  }
  // ---- epilogue 2: store h2 (f32) + BN partial sums ----
  float s1[2] = {0.f, 0.f}, s2[2] = {0.f, 0.f};
#pragma unroll
  for (int ct = 0; ct < 2; ++ct) {
    int col = colb2 + ct * 16 + l16;
    float cb = c2[col];
#pragma unroll
    for (int rt = 0; rt < 2; ++rt)
#pragma unroll
      for (int r = 0; r < 4; ++r) {
        int row = rt * 16 + quad * 4 + r;
        int t = tbase + row;
        if (t < NTGT) {
          float v = acc2[rt][ct][r] + cb;
          h2[(size_t)t * LDIM + col] = v;
          s1[ct] += v; s2[ct] += v * v;
        }
      }
  }
#pragma unroll
  for (int ct = 0; ct < 2; ++ct) {
    float a = s1[ct], b = s2[ct];
    a += __shfl_down(a, 32); b += __shfl_down(b, 32);
    a += __shfl_down(a, 16); b += __shfl_down(b, 16);
    if (lane < 16) {
      atomicAdd(&stats[colb2 + ct * 16 + l16], a);
      atomicAdd(&stats[128 + colb2 + ct * 16 + l16], b);
    }
  }
}

// ---------- BN finalize + apply ----------
__global__ void k_bnfin(const float* __restrict__ stats, const float* __restrict__ gamma,
                        const float* __restrict__ beta, float* __restrict__ ss) {
  int c = threadIdx.x;
  if (c < 128) {
    float mu = stats[c] * (1.0f / NTGT);
    float var = stats[128 + c] * (1.0f / NTGT) - mu * mu;
    float rs = rsqrtf(var + 1e-5f);
    float sc = gamma[c] * rs;
    ss[c] = sc;
    ss[128 + c] = beta[c] - mu * sc;
  }
}

__global__ void k_bnapply(const float* __restrict__ h2, const float* __restrict__ ss,
                          float* __restrict__ out) {
  int i = blockIdx.x * 256 + threadIdx.x;
  const int total = NTGT * LDIM / 4;
  const float4* h4 = (const float4*)h2;
  const float4* sc4 = (const float4*)ss;
  const float4* sh4 = (const float4*)(ss + 128);
  float4* o4 = (float4*)out;
  for (; i < total; i += gridDim.x * 256) {
    int cg = i & 31;
    float4 h = h4[i], sc = sc4[cg], sh = sh4[cg];
    float4 r = { h.x * sc.x + sh.x, h.y * sc.y + sh.y,
                 h.z * sc.z + sh.z, h.w * sc.w + sh.w };
    o4[i] = r;
  }
}

// ---------- launch ----------
extern "C" void kernel_launch(void* const* d_in, const int* in_sizes, int n_in,
                              void* d_out, int out_size, void* d_ws, size_t ws_size,
                              hipStream_t stream) {
  (void)in_sizes; (void)n_in; (void)out_size; (void)ws_size;
  const float* xs    = (const float*)d_in[0];
  const float* xt    = (const float*)d_in[1];
  const int*   ei    = (const int*)d_in[2];
  const float* ea    = (const float*)d_in[3];
  const float* xu    = (const float*)d_in[4];
  const float* W1    = (const float*)d_in[5];
  const float* b1    = (const float*)d_in[6];
  const float* W2    = (const float*)d_in[7];
  const float* b2    = (const float*)d_in[8];
  const float* U1    = (const float*)d_in[9];
  const float* c1    = (const float*)d_in[10];
  const float* U2    = (const float*)d_in[11];
  const float* c2    = (const float*)d_in[12];
  const float* gamma = (const float*)d_in[13];
  const float* beta  = (const float*)d_in[14];

  char* ws = (char*)d_ws;
  u16* w1p   = (u16*)(ws + 0x0);        // 8 panels * 20480B = 163840
  u16* w2p   = (u16*)(ws + 0x40000);    // 163840
  u16* u1p   = (u16*)(ws + 0x80000);    // 16 * 40960 = 655360
  u16* u2p   = (u16*)(ws + 0x130000);   // 16 * 10240 = 163840 (+ overread slack)
  int* cnt   = (int*)(ws + 0x170000);   // 50000 * 4
  int* rowst = (int*)(ws + 0x1A8000);   // 50001 * 4
  int* cur   = (int*)(ws + 0x1E0000);   // 50000 * 4
  int* pos   = (int*)(ws + 0x220000);   // 640000 * 4
  float* stats = (float*)(ws + 0x4A0000); // colsum[128] | colsq[128]
  float* ss    = stats + 256;             // scale[128] | shift[128]
  float* h2  = (float*)(ws + 0x4B0000); // 50000*128*4 = 25.6 MB
  u16* msg   = (u16*)(ws + 0x1D80000);  // 640000*256*2 = 327.68 MB

  const int* srcp = ei;
  const int* tgtp = ei + NEDGE;

  hipMemsetAsync(cnt, 0, NTGT * 4, stream);
  hipMemsetAsync(stats, 0, 256 * 4, stream);
  k_prep<<<56, 256, 0, stream>>>(W1, W2, U1, U2, w1p, w2p, u1p, u2p);
  k_count<<<2500, 256, 0, stream>>>(tgtp, cnt);
  k_scan<<<1, 1024, 0, stream>>>(cnt, rowst, cur);
  k_pos<<<2500, 256, 0, stream>>>(tgtp, cur, pos);
  k_edge<<<10000, 256, 0, stream>>>(xs, srcp, ea, w1p, w2p, b1, b2, pos, msg);
  k_node<<<1563, 256, 0, stream>>>(xt, xu, msg, rowst, u1p, u2p, c1, c2, h2, stats);
  k_bnfin<<<1, 128, 0, stream>>>(stats, gamma, beta, ss);
  k_bnapply<<<6250, 256, 0, stream>>>(h2, ss, (float*)d_out);
}

// Round 2
// 999.420 us; speedup vs baseline: 1.2810x; 1.2810x over previous
//
#include <hip/hip_runtime.h>

typedef unsigned int u32;
typedef unsigned short u16;
typedef __attribute__((ext_vector_type(8))) short short8;
typedef __attribute__((ext_vector_type(8))) unsigned short ushort8v;
typedef __attribute__((ext_vector_type(4))) unsigned short ushort4v;
typedef __attribute__((ext_vector_type(4))) float f32x4;

#define NSRC 50000
#define NTGT 50000
#define NEDGE 640000
#define LDIM 128
#define SLOPE 0.01f

#define MFMA(a, b, c) __builtin_amdgcn_mfma_f32_16x16x32_bf16((a), (b), (c), 0, 0, 0)

// ---------- helpers ----------
__device__ __forceinline__ u16 f2bf(float f) {
  union { float f; u32 u; } v; v.f = f;
  u32 r = v.u + 0x7FFFu + ((v.u >> 16) & 1u);   // RNE
  return (u16)(r >> 16);
}
__device__ __forceinline__ float bf2f(u16 h) {
  union { u32 u; float f; } v; v.u = ((u32)h) << 16; return v.f;
}

// ---------- weight prep: f32 [K][N] -> bf16 fragment-linear ----------
// pack[((kc*(N/16)+cb)*64 + lane)*8 + j] = W[kc*32 + (lane>>4)*8 + j][cb*16 + (lane&15)]
// => a wave's B-fragment for (kc, cb) is 64 lanes x 16B, fully contiguous (1 KB).
__device__ __forceinline__ void pack_one(const float* __restrict__ src, u16* __restrict__ dst,
                                         int N, int kc, int cb, int lane) {
  int quad = lane >> 4, l16 = lane & 15;
  const float* s = src + (size_t)(kc * 32 + quad * 8) * N + cb * 16 + l16;
  u16* o = dst + ((size_t)(kc * (N / 16) + cb) * 64 + lane) * 8;
  ushort8v p;
#pragma unroll
  for (int j = 0; j < 8; ++j) p[j] = f2bf(s[(size_t)j * N]);
  *(ushort8v*)o = p;
}

__global__ void k_prep(const float* __restrict__ W1, const float* __restrict__ W2,
                       const float* __restrict__ U1, const float* __restrict__ U2,
                       u16* __restrict__ w1p, u16* __restrict__ w2p,
                       u16* __restrict__ u1p, u16* __restrict__ u2p) {
  int id = blockIdx.x * 256 + threadIdx.x;
  // W1: 8 kc x 16 cb x 64 = 8192 ; W2: 8192 ; U1: 16x32x64 = 32768 ; U2: 16x8x64 = 8192
  if (id < 8192) {
    int l = id, lane = l & 63, g = l >> 6;           // g = kc*16+cb
    pack_one(W1, w1p, 256, g >> 4, g & 15, lane);
  } else if (id < 16384) {
    int l = id - 8192, lane = l & 63, g = l >> 6;
    pack_one(W2, w2p, 256, g >> 4, g & 15, lane);
  } else if (id < 49152) {
    int l = id - 16384, lane = l & 63, g = l >> 6;   // g = kc*32+cb
    pack_one(U1, u1p, 512, g >> 5, g & 31, lane);
  } else if (id < 57344) {
    int l = id - 49152, lane = l & 63, g = l >> 6;   // g = kc*8+cb
    pack_one(U2, u2p, 128, g >> 3, g & 7, lane);
  }
}

// ---------- counting sort by target ----------
__global__ void k_count(const int* __restrict__ tgt, int* __restrict__ cnt,
                        int* __restrict__ rank) {
  int e = blockIdx.x * 256 + threadIdx.x;
  if (e < NEDGE) rank[e] = atomicAdd(&cnt[tgt[e]], 1);
}

__global__ void k_scan(const int* __restrict__ cnt, int* __restrict__ rowstart) {
  __shared__ int part[1024];
  int tid = threadIdx.x;
  int base = tid * 49;                       // 1024*49 = 50176 >= 50000
  int s = 0;
  for (int i = 0; i < 49; ++i) { int idx = base + i; if (idx < NTGT) s += cnt[idx]; }
  part[tid] = s;
  __syncthreads();
  for (int off = 1; off < 1024; off <<= 1) {
    int v = (tid >= off) ? part[tid - off] : 0;
    __syncthreads();
    part[tid] += v;
    __syncthreads();
  }
  int run = (tid > 0) ? part[tid - 1] : 0;
  for (int i = 0; i < 49; ++i) {
    int idx = base + i;
    if (idx < NTGT) { rowstart[idx] = run; run += cnt[idx]; }
  }
  if (tid == 1023) rowstart[NTGT] = part[1023];
}

__global__ void k_pos(const int* __restrict__ tgt, const int* __restrict__ rowstart,
                      int* __restrict__ pos) {
  int e = blockIdx.x * 256 + threadIdx.x;
  if (e < NEDGE) pos[e] = rowstart[tgt[e]] + pos[e];   // pos aliases rank
}

// ---------- edge MLP: 64 edges/block; barrier-free K loops, B-frags from L2 ----------
__global__ __launch_bounds__(256, 4) void k_edge(
    const float* __restrict__ xs, const int* __restrict__ srcp,
    const float* __restrict__ ea,
    const u16* __restrict__ w1p, const u16* __restrict__ w2p,
    const float* __restrict__ b1, const float* __restrict__ b2,
    const int* __restrict__ pos, u16* __restrict__ msg) {
  __shared__ u16 tile[64][264];    // 33792 B, only LDS in kernel
  const int tid = threadIdx.x;
  const int ebase = blockIdx.x * 64;

  // ---- stage: gather x_s[src] | edge_attr, f32 -> bf16 ----
  {
    const int et = tid >> 2, p = tid & 3;
    const float* srow;
    if (p < 2) {
      int sidx = srcp[ebase + et];
      srow = xs + (size_t)sidx * LDIM + p * 64;
    } else {
      srow = ea + (size_t)(ebase + et) * LDIM + (p - 2) * 64;
    }
    const float4* f4 = (const float4*)srow;
    u16* dst = &tile[et][p * 64];
#pragma unroll
    for (int i = 0; i < 8; ++i) {
      float4 a = f4[2 * i], b = f4[2 * i + 1];
      ushort8v pk = { f2bf(a.x), f2bf(a.y), f2bf(a.z), f2bf(a.w),
                      f2bf(b.x), f2bf(b.y), f2bf(b.z), f2bf(b.w) };
      *(ushort8v*)(dst + i * 8) = pk;
    }
  }
  __syncthreads();

  const int lane = tid & 63, wid = tid >> 6;
  const int quad = lane >> 4, l16 = lane & 15;
  const int colb = wid * 64;
  const short8* __restrict__ w1f = (const short8*)w1p;
  const short8* __restrict__ w2f = (const short8*)w2p;

  f32x4 acc[4][4];
#pragma unroll
  for (int a = 0; a < 4; ++a)
#pragma unroll
    for (int b = 0; b < 4; ++b) acc[a][b] = (f32x4){0.f, 0.f, 0.f, 0.f};

  // ---- GEMM1: t = leaky(in @ W1 + b1) ---- (no barriers inside)
#pragma unroll 2
  for (int kc = 0; kc < 8; ++kc) {
    short8 af[4], bfr[4];
#pragma unroll
    for (int ct = 0; ct < 4; ++ct)
      bfr[ct] = w1f[(size_t)(kc * 16 + wid * 4 + ct) * 64 + lane];
#pragma unroll
    for (int rt = 0; rt < 4; ++rt)
      af[rt] = *(const short8*)&tile[rt * 16 + l16][kc * 32 + quad * 8];
#pragma unroll
    for (int rt = 0; rt < 4; ++rt)
#pragma unroll
      for (int ct = 0; ct < 4; ++ct)
        acc[rt][ct] = MFMA(af[rt], bfr[ct], acc[rt][ct]);
  }
  __syncthreads();   // all A-reads done before overwrite
  // epilogue 1 -> tile (bf16)
#pragma unroll
  for (int ct = 0; ct < 4; ++ct) {
    int col = colb + ct * 16 + l16;
    float bias = b1[col];
#pragma unroll
    for (int rt = 0; rt < 4; ++rt)
#pragma unroll
      for (int r = 0; r < 4; ++r) {
        int row = rt * 16 + quad * 4 + r;
        float v = acc[rt][ct][r] + bias;
        v = v > 0.f ? v : SLOPE * v;
        tile[row][col] = f2bf(v);
      }
  }
  __syncthreads();

  // ---- GEMM2: msg = t @ W2 + b2 ----
#pragma unroll
  for (int a = 0; a < 4; ++a)
#pragma unroll
    for (int b = 0; b < 4; ++b) acc[a][b] = (f32x4){0.f, 0.f, 0.f, 0.f};
#pragma unroll 2
  for (int kc = 0; kc < 8; ++kc) {
    short8 af[4], bfr[4];
#pragma unroll
    for (int ct = 0; ct < 4; ++ct)
      bfr[ct] = w2f[(size_t)(kc * 16 + wid * 4 + ct) * 64 + lane];
#pragma unroll
    for (int rt = 0; rt < 4; ++rt)
      af[rt] = *(const short8*)&tile[rt * 16 + l16][kc * 32 + quad * 8];
#pragma unroll
    for (int rt = 0; rt < 4; ++rt)
#pragma unroll
      for (int ct = 0; ct < 4; ++ct)
        acc[rt][ct] = MFMA(af[rt], bfr[ct], acc[rt][ct]);
  }
  __syncthreads();
  // epilogue 2 -> tile (bf16 msg)
#pragma unroll
  for (int ct = 0; ct < 4; ++ct) {
    int col = colb + ct * 16 + l16;
    float bias = b2[col];
#pragma unroll
    for (int rt = 0; rt < 4; ++rt)
#pragma unroll
      for (int r = 0; r < 4; ++r) {
        int row = rt * 16 + quad * 4 + r;
        tile[row][col] = f2bf(acc[rt][ct][r] + bias);
      }
  }
  __syncthreads();

  // ---- scatter rows to target-sorted msg buffer ----
  {
    const int et = tid >> 2, p = tid & 3;
    const int gp = pos[ebase + et];
    u16* dst = msg + (size_t)gp * 256 + p * 64;
    const u16* sl = &tile[et][p * 64];
#pragma unroll
    for (int i = 0; i < 8; ++i)
      *(ushort8v*)(dst + i * 8) = *(const ushort8v*)(sl + i * 8);
  }
}

// ---------- node update: 32 targets/block ----------
__global__ __launch_bounds__(256, 4) void k_node(
    const float* __restrict__ xt, const float* __restrict__ xu,
    const u16* __restrict__ msg, const int* __restrict__ rowstart,
    const u16* __restrict__ u1p, const u16* __restrict__ u2p,
    const float* __restrict__ c1, const float* __restrict__ c2,
    float* __restrict__ h2, float* __restrict__ stats) {
  __shared__ u16 ain[32][520];   // 33280 B
  const int tid = threadIdx.x;
  const int lane = tid & 63, wid = tid >> 6;
  const int quad = lane >> 4, l16 = lane & 15;
  const int tbase = blockIdx.x * 32;

  // ---- stage: one wave per target slot; coalesced 2-row aggregation ----
  for (int s = wid; s < 32; s += 4) {
    int t = tbase + s;
    if (t < NTGT) {
      {
        float4 v; int col;
        if (lane < 32) { v = ((const float4*)(xt + (size_t)t * LDIM))[lane]; col = lane * 4; }
        else           { v = ((const float4*)xu)[lane - 32]; col = 384 + (lane - 32) * 4; }
        ushort4v p = { f2bf(v.x), f2bf(v.y), f2bf(v.z), f2bf(v.w) };
        *(ushort4v*)&ain[s][col] = p;
      }
      int rs = rowstart[t], re = rowstart[t + 1];
      float acc8[8] = {0.f, 0.f, 0.f, 0.f, 0.f, 0.f, 0.f, 0.f};
      const u16* mb = msg + ((size_t)rs + (lane >> 5)) * 256 + (lane & 31) * 8;
      int n = re - rs, nfull = n & ~1;
      for (int r = 0; r < nfull; r += 2) {
        ushort8v m = *(const ushort8v*)(mb + (size_t)r * 256);
#pragma unroll
        for (int j = 0; j < 8; ++j) acc8[j] += bf2f(m[j]);
      }
      if (n & 1) {
        if (lane < 32) {
          ushort8v m = *(const ushort8v*)(msg + (size_t)(re - 1) * 256 + lane * 8);
#pragma unroll
          for (int j = 0; j < 8; ++j) acc8[j] += bf2f(m[j]);
        }
      }
#pragma unroll
      for (int j = 0; j < 8; ++j) acc8[j] += __shfl_down(acc8[j], 32);
      if (lane < 32) {
        ushort8v p;
#pragma unroll
        for (int j = 0; j < 8; ++j) p[j] = f2bf(acc8[j]);
        *(ushort8v*)&ain[s][128 + lane * 8] = p;
      }
    } else {
      ushort8v z = {0, 0, 0, 0, 0, 0, 0, 0};
      *(ushort8v*)&ain[s][lane * 8] = z;   // zero the 512 data cols
    }
  }
  __syncthreads();

  const short8* __restrict__ u1f = (const short8*)u1p;
  const short8* __restrict__ u2f = (const short8*)u2p;

  // ---- GEMM1: h1 = leaky(ain @ U1 + c1), N=512 (barrier-free K loop) ----
  f32x4 acc[2][2][4];   // [half][rowtile][coltile]
#pragma unroll
  for (int h = 0; h < 2; ++h)
#pragma unroll
    for (int a = 0; a < 2; ++a)
#pragma unroll
      for (int b = 0; b < 4; ++b) acc[h][a][b] = (f32x4){0.f, 0.f, 0.f, 0.f};

#pragma unroll 2
  for (int kc = 0; kc < 16; ++kc) {
    short8 af[2];
#pragma unroll
    for (int rt = 0; rt < 2; ++rt)
      af[rt] = *(const short8*)&ain[rt * 16 + l16][kc * 32 + quad * 8];
#pragma unroll
    for (int h = 0; h < 2; ++h) {
      short8 bfr[4];
#pragma unroll
      for (int ct = 0; ct < 4; ++ct)
        bfr[ct] = u1f[(size_t)(kc * 32 + h * 16 + wid * 4 + ct) * 64 + lane];
#pragma unroll
      for (int rt = 0; rt < 2; ++rt)
#pragma unroll
        for (int ct = 0; ct < 4; ++ct)
          acc[h][rt][ct] = MFMA(af[rt], bfr[ct], acc[h][rt][ct]);
    }
  }
  __syncthreads();
  // epilogue 1 -> ain (h1, bf16)
#pragma unroll
  for (int h = 0; h < 2; ++h)
#pragma unroll
    for (int ct = 0; ct < 4; ++ct) {
      int col = h * 256 + wid * 64 + ct * 16 + l16;
      float cb = c1[col];
#pragma unroll
      for (int rt = 0; rt < 2; ++rt)
#pragma unroll
        for (int r = 0; r < 4; ++r) {
          int row = rt * 16 + quad * 4 + r;
          float v = acc[h][rt][ct][r] + cb;
          v = v > 0.f ? v : SLOPE * v;
          ain[row][col] = f2bf(v);
        }
    }
  __syncthreads();

  // ---- GEMM2: h2 = h1 @ U2 + c2, N=128 ----
  const int colb2 = wid * 32;
  f32x4 acc2[2][2];
#pragma unroll
  for (int a = 0; a < 2; ++a)
#pragma unroll
    for (int b = 0; b < 2; ++b) acc2[a][b] = (f32x4){0.f, 0.f, 0.f, 0.f};
#pragma unroll 4
  for (int kc = 0; kc < 16; ++kc) {
    short8 af[2], bfr[2];
#pragma unroll
    for (int ct = 0; ct < 2; ++ct)
      bfr[ct] = u2f[(size_t)(kc * 8 + wid * 2 + ct) * 64 + lane];
#pragma unroll
    for (int rt = 0; rt < 2; ++rt)
      af[rt] = *(const short8*)&ain[rt * 16 + l16][kc * 32 + quad * 8];
#pragma unroll
    for (int rt = 0; rt < 2; ++rt)
#pragma unroll
      for (int ct = 0; ct < 2; ++ct)
        acc2[rt][ct] = MFMA(af[rt], bfr[ct], acc2[rt][ct]);
  }
  // ---- epilogue 2: store h2 (f32) + BN partial sums ----
  float s1[2] = {0.f, 0.f}, s2[2] = {0.f, 0.f};
#pragma unroll
  for (int ct = 0; ct < 2; ++ct) {
    int col = colb2 + ct * 16 + l16;
    float cb = c2[col];
#pragma unroll
    for (int rt = 0; rt < 2; ++rt)
#pragma unroll
      for (int r = 0; r < 4; ++r) {
        int row = rt * 16 + quad * 4 + r;
        int t = tbase + row;
        if (t < NTGT) {
          float v = acc2[rt][ct][r] + cb;
          h2[(size_t)t * LDIM + col] = v;
          s1[ct] += v; s2[ct] += v * v;
        }
      }
  }
#pragma unroll
  for (int ct = 0; ct < 2; ++ct) {
    float a = s1[ct], b = s2[ct];
    a += __shfl_down(a, 32); b += __shfl_down(b, 32);
    a += __shfl_down(a, 16); b += __shfl_down(b, 16);
    if (lane < 16) {
      atomicAdd(&stats[colb2 + ct * 16 + l16], a);
      atomicAdd(&stats[128 + colb2 + ct * 16 + l16], b);
    }
  }
}

// ---------- BN finalize + apply ----------
__global__ void k_bnfin(const float* __restrict__ stats, const float* __restrict__ gamma,
                        const float* __restrict__ beta, float* __restrict__ ss) {
  int c = threadIdx.x;
  if (c < 128) {
    float mu = stats[c] * (1.0f / NTGT);
    float var = stats[128 + c] * (1.0f / NTGT) - mu * mu;
    float rs = rsqrtf(var + 1e-5f);
    float sc = gamma[c] * rs;
    ss[c] = sc;
    ss[128 + c] = beta[c] - mu * sc;
  }
}

__global__ void k_bnapply(const float* __restrict__ h2, const float* __restrict__ ss,
                          float* __restrict__ out) {
  int i = blockIdx.x * 256 + threadIdx.x;
  const int total = NTGT * LDIM / 4;
  const float4* h4 = (const float4*)h2;
  const float4* sc4 = (const float4*)ss;
  const float4* sh4 = (const float4*)(ss + 128);
  float4* o4 = (float4*)out;
  for (; i < total; i += gridDim.x * 256) {
    int cg = i & 31;
    float4 h = h4[i], sc = sc4[cg], sh = sh4[cg];
    float4 r = { h.x * sc.x + sh.x, h.y * sc.y + sh.y,
                 h.z * sc.z + sh.z, h.w * sc.w + sh.w };
    o4[i] = r;
  }
}

// ---------- launch ----------
extern "C" void kernel_launch(void* const* d_in, const int* in_sizes, int n_in,
                              void* d_out, int out_size, void* d_ws, size_t ws_size,
                              hipStream_t stream) {
  (void)in_sizes; (void)n_in; (void)out_size; (void)ws_size;
  const float* xs    = (const float*)d_in[0];
  const float* xt    = (const float*)d_in[1];
  const int*   ei    = (const int*)d_in[2];
  const float* ea    = (const float*)d_in[3];
  const float* xu    = (const float*)d_in[4];
  const float* W1    = (const float*)d_in[5];
  const float* b1    = (const float*)d_in[6];
  const float* W2    = (const float*)d_in[7];
  const float* b2    = (const float*)d_in[8];
  const float* U1    = (const float*)d_in[9];
  const float* c1    = (const float*)d_in[10];
  const float* U2    = (const float*)d_in[11];
  const float* c2    = (const float*)d_in[12];
  const float* gamma = (const float*)d_in[13];
  const float* beta  = (const float*)d_in[14];

  char* ws = (char*)d_ws;
  u16* w1p   = (u16*)(ws + 0x000000);   // 131072 B
  u16* w2p   = (u16*)(ws + 0x020000);   // 131072 B
  u16* u1p   = (u16*)(ws + 0x040000);   // 524288 B
  u16* u2p   = (u16*)(ws + 0x0C0000);   // 131072 B
  int* cnt   = (int*)(ws + 0x0E0000);   // 200000 B
  int* rowst = (int*)(ws + 0x120000);   // 200004 B
  int* pos   = (int*)(ws + 0x160000);   // 2560000 B (rank, then final pos in-place)
  float* stats = (float*)(ws + 0x400000); // colsum[128] | colsq[128]
  float* ss    = stats + 256;             // scale[128] | shift[128]
  float* h2  = (float*)(ws + 0x410000); // 25.6 MB
  u16* msg   = (u16*)(ws + 0x1C80000);  // 327.68 MB

  const int* srcp = ei;
  const int* tgtp = ei + NEDGE;

  hipMemsetAsync(cnt, 0, NTGT * 4, stream);
  hipMemsetAsync(stats, 0, 256 * 4, stream);
  k_prep<<<224, 256, 0, stream>>>(W1, W2, U1, U2, w1p, w2p, u1p, u2p);
  k_count<<<2500, 256, 0, stream>>>(tgtp, cnt, pos);
  k_scan<<<1, 1024, 0, stream>>>(cnt, rowst);
  k_pos<<<2500, 256, 0, stream>>>(tgtp, rowst, pos);
  k_edge<<<10000, 256, 0, stream>>>(xs, srcp, ea, w1p, w2p, b1, b2, pos, msg);
  k_node<<<1563, 256, 0, stream>>>(xt, xu, msg, rowst, u1p, u2p, c1, c2, h2, stats);
  k_bnfin<<<1, 128, 0, stream>>>(stats, gamma, beta, ss);
  k_bnapply<<<6250, 256, 0, stream>>>(h2, ss, (float*)d_out);
}